// Round 9
// baseline (346.713 us; speedup 1.0000x reference)
//
#include <hip/hip_runtime.h>

#define DEV static __device__ __forceinline__

typedef float f32x4 __attribute__((ext_vector_type(4)));
typedef int i32x4 __attribute__((ext_vector_type(4)));
typedef __bf16 bf16x8 __attribute__((ext_vector_type(8)));
typedef unsigned short u16x8 __attribute__((ext_vector_type(8)));
typedef unsigned short u16x4 __attribute__((ext_vector_type(4)));

#define MFMA(a, b, c) __builtin_amdgcn_mfma_f32_16x16x32_bf16((a), (b), (c), 0, 0, 0)

// fine-grained barriers: counted vmcnt (never a just-issued drain) + s_barrier.
#define WAIT5_BARRIER() asm volatile("s_waitcnt vmcnt(5)\n\ts_barrier" ::: "memory")
#define VM0_BARRIER()   asm volatile("s_waitcnt vmcnt(0)\n\ts_barrier" ::: "memory")
#define LGKM_BARRIER()  asm volatile("s_waitcnt lgkmcnt(0)\n\ts_barrier" ::: "memory")
#define VM_DRAIN()      asm volatile("s_waitcnt vmcnt(0)" ::: "memory")

// B=8, T=2048, C=1024, H=64
#define TT 2048
#define CE 1024
#define HS 64

// ws layout (ushort elements unless noted). Total ~16.8 MB; round-6 profile
// shows the harness poisons a 256 MiB workspace arena, so this is safe.
#define WBT_E 0                   // [3][64 n][1024 k] bf16 (Wq scaled by log2e/32)
#define Q_E   196608              // [B*T][64] bf16
#define K_E   (Q_E + 1048576)
#define VT_E  (K_E + 1048576)     // [B][64 h][2048 t] bf16
#define PO_E  (VT_E + 1048576)    // [1152 slots][64 row][64 h] bf16 partial O
#define PML_E (PO_E + 4718592)    // float [1152][64 row][2] {m,l}
#define CNT_E (PML_E + 294912)    // int [256] chunk-completion counters

DEV unsigned short cvt_bf16(float f) {
    unsigned int u = __builtin_bit_cast(unsigned int, f);
    u += 0x7FFFu + ((u >> 16) & 1u);   // RNE (finite inputs)
    return (unsigned short)(u >> 16);
}

DEV float bf2f(unsigned short v) {
    unsigned int u = ((unsigned int)v) << 16;
    return __builtin_bit_cast(float, u);
}

DEV bf16x8 ld_bf8(const unsigned short* p) {
    union { u16x8 u; bf16x8 b; } v;
    v.u = *(const u16x8*)p;
    return v.b;
}

DEV bf16x8 as_bf8(u16x8 u) {
    union { u16x8 u; bf16x8 b; } v;
    v.u = u;
    return v.b;
}

// async global->LDS, 16B/lane; LDS dst is WAVE-UNIFORM base (+lane*16 by HW)
DEV void glds16(const void* g, void* l) {
    __builtin_amdgcn_global_load_lds(
        (const __attribute__((address_space(1))) void*)g,
        (__attribute__((address_space(3))) void*)l, 16, 0, 0);
}

// ---------------- kernel 1: W fp32 -> bf16 transposed [n][k] ----------------
__global__ __launch_bounds__(256) void wconv_kernel(
        const float* __restrict__ Wq, const float* __restrict__ Wk,
        const float* __restrict__ Wv, unsigned short* __restrict__ wbt) {
    __shared__ unsigned short Tr[64 * 72];
    const int blk = blockIdx.x;
    const int head = blk >> 4, kt = blk & 15;
    const int k0 = kt * 64;
    const float* W = (head == 0) ? Wq : ((head == 1) ? Wk : Wv);
    const float sc = (head == 0) ? 0.045084220027780106f : 1.0f;  // log2(e)/32
    const int t = threadIdx.x;
    const int rrow = t >> 4, c4 = (t & 15) * 4;
    for (int i = 0; i < 4; ++i) {
        int krow = rrow + i * 16;
        f32x4 f = *(const f32x4*)(W + (size_t)(k0 + krow) * 64 + c4);
        Tr[(c4 + 0) * 72 + krow] = cvt_bf16(f[0] * sc);
        Tr[(c4 + 1) * 72 + krow] = cvt_bf16(f[1] * sc);
        Tr[(c4 + 2) * 72 + krow] = cvt_bf16(f[2] * sc);
        Tr[(c4 + 3) * 72 + krow] = cvt_bf16(f[3] * sc);
    }
    __syncthreads();
    const int n = t >> 2, off = (t & 3) * 16;
    u16x8 a0 = *(const u16x8*)&Tr[n * 72 + off];
    u16x8 a1 = *(const u16x8*)&Tr[n * 72 + off + 8];
    unsigned short* dst = wbt + head * 65536 + n * 1024 + k0 + off;
    *(u16x8*)dst = a0;
    *(u16x8*)(dst + 8) = a1;
}

// ---------------- kernel 2: projection q,k = x@W; v transposed -> vt --------
// Big-slot structure (round-3): 256 blocks (1/CU) x 8 waves; block tile
// 64 rows x 192 cols, K-step 64, 16 slots. 40 glds/slot = uniform 5/wave,
// 3 LDS buffers (120 KB), depth-2 ring, vmcnt(5)+barrier.
// Also zeroes the flash chunk-completion counters (visible to flash via the
// kernel-boundary on the same stream).
__global__ __launch_bounds__(512, 2) void proj_kernel(
        const float* __restrict__ x, const unsigned short* __restrict__ wbt,
        unsigned short* __restrict__ qws, unsigned short* __restrict__ kws,
        unsigned short* __restrict__ vtws, int* __restrict__ cnt) {
    __shared__ __align__(16) float Xt0[4096], Xt1[4096], Xt2[4096];          // 3x16 KB
    __shared__ __align__(16) unsigned short Wt0[12288], Wt1[12288], Wt2[12288]; // 3x24 KB
    __shared__ __align__(16) unsigned short TT2[64 * 72];  // v-transpose scratch

    const int t = threadIdx.x;
    if (t == 0) cnt[blockIdx.x] = 0;            // 256 blocks, 256 counters
    const int lane = t & 63, w = t >> 6;        // w in 0..7
    const int quad = lane >> 4, c = lane & 15;
    const int wm = w & 1, wn = w >> 1;          // 32-row half, 48-col quarter
    const int t0 = blockIdx.x * 64;
    const int ck7 = c & 7;

    // ---- staging geometry (content chunk = phys chunk ^ (row&7 | col&7)) --
    // x: glds g covers 4 rows (local rows w*8+g*4 .. +3), 16 chunks of 16B
    const int sxr = lane >> 4;                         // row-in-group 0..3
    const int sxc0 = (lane & 15) ^ sxr;                // key (0*4+sxr)&7
    const int sxc1 = (lane & 15) ^ ((4 + sxr) & 7);    // key (4+sxr)&7
    const float* xg0 = x + (size_t)(t0 + w * 8 + 0 + sxr) * CE + sxc0 * 4;
    const float* xg1 = x + (size_t)(t0 + w * 8 + 4 + sxr) * CE + sxc1 * 4;
    // W: glds g covers 8 cols (local cols w*24+g*8 .. +7), 8 chunks of 16B
    const int swc = lane >> 3;                         // col-in-group 0..7
    const int swk = (lane & 7) ^ swc;                  // key = col&7 = swc
    const unsigned short* wg0 = wbt + (size_t)(w * 24 + 0 + swc) * 1024 + swk * 8;
    const unsigned short* wg1 = wbt + (size_t)(w * 24 + 8 + swc) * 1024 + swk * 8;
    const unsigned short* wg2 = wbt + (size_t)(w * 24 + 16 + swc) * 1024 + swk * 8;

#define PSTAGE(XD, WD, ks) { \
    const int kf = (ks) * 64; \
    glds16(xg0 + kf, &XD[(w * 8 + 0) * 64]); \
    glds16(xg1 + kf, &XD[(w * 8 + 4) * 64]); \
    glds16(wg0 + kf, &WD[(w * 24 + 0) * 64]); \
    glds16(wg1 + kf, &WD[(w * 24 + 8) * 64]); \
    glds16(wg2 + kf, &WD[(w * 24 + 16) * 64]); }

    f32x4 acc[2][3] = {};

    // prologue: stage k-slices 0,1 into buffers 0,1 (10 glds/wave in flight)
    PSTAGE(Xt0, Wt0, 0)
    PSTAGE(Xt1, Wt1, 1)
    // no barrier: first PITER's WAIT5_BARRIER covers buffer 0 + syncs waves

#define PITER(step, XT, WT, XD, WD) { \
    WAIT5_BARRIER(); \
    bf16x8 af[2][2]; \
    _Pragma("unroll") for (int rf = 0; rf < 2; ++rf) \
    _Pragma("unroll") for (int kk = 0; kk < 2; ++kk) { \
        const int row = wm * 32 + rf * 16 + c; \
        const int lc = kk * 8 + quad * 2; \
        f32x4 v0 = *(const f32x4*)&XT[row * 64 + ((lc ^ ck7) * 4)]; \
        f32x4 v1 = *(const f32x4*)&XT[row * 64 + (((lc + 1) ^ ck7) * 4)]; \
        u16x8 ap; \
        _Pragma("unroll") for (int j = 0; j < 4; ++j) { \
            ap[j] = cvt_bf16(v0[j]); ap[4 + j] = cvt_bf16(v1[j]); } \
        af[rf][kk] = as_bf8(ap); \
    } \
    _Pragma("unroll") for (int nt = 0; nt < 3; ++nt) \
    _Pragma("unroll") for (int kk = 0; kk < 2; ++kk) { \
        const int col = wn * 48 + nt * 16 + c; \
        bf16x8 bb = ld_bf8(&WT[col * 64 + (((kk * 4 + quad) ^ ck7) * 8)]); \
        acc[0][nt] = MFMA(af[0][kk], bb, acc[0][nt]); \
        acc[1][nt] = MFMA(af[1][kk], bb, acc[1][nt]); \
    } \
    PSTAGE(XD, WD, (((step) + 2) & 15)) }

    for (int s = 0; s < 15; s += 3) {
        PITER(s + 0, Xt0, Wt0, Xt2, Wt2)
        PITER(s + 1, Xt1, Wt1, Xt0, Wt0)
        PITER(s + 2, Xt2, Wt2, Xt1, Wt1)
    }
    PITER(15, Xt0, Wt0, Xt2, Wt2)   // tail: stages dummy (slice wraps to 1)
#undef PITER
#undef PSTAGE

    // epilogue: q,k direct; v transposed via LDS (64 h x 64 t, stride 72)
#pragma unroll
    for (int rf = 0; rf < 2; ++rf) {
#pragma unroll
        for (int nt = 0; nt < 3; ++nt) {
            int col = wn * 48 + nt * 16 + c;
            f32x4 a = acc[rf][nt];
#pragma unroll
            for (int r4 = 0; r4 < 4; ++r4) {
                int row = wm * 32 + rf * 16 + quad * 4 + r4;
                size_t tg = (size_t)(t0 + row);
                unsigned short hv = cvt_bf16(a[r4]);
                if (col < 64)       qws[tg * HS + col] = hv;
                else if (col < 128) kws[tg * HS + col - 64] = hv;
                else                TT2[(col - 128) * 72 + row] = hv;
            }
        }
    }
    __syncthreads();   // full drain: also retires the tail dummy glds
    {
        int h = t >> 3, off = (t & 7) * 8;
        u16x8 v = *(const u16x8*)&TT2[h * 72 + off];
        int b = t0 >> 11, tl0 = t0 & 2047;
        *(u16x8*)(vtws + (size_t)(b * 64 + h) * TT + tl0 + off) = v;
    }
}

// ---------------- kernel 3: flash + fused combine (last chunk merges) ------
// 1152 blocks = 8 b x 144 chunks (balanced 4-tile chunks, round-7 structure).
// After storing partials, each block does __threadfence (release) +
// atomicAdd on cnt[b*32+qt] (device-scope, m20); the block seeing
// old == nc-1 fences (acquire) and merges all nc chunk partials for its
// (b,qt) into the final output inline (round-8 predicated 8-slot batch).
// Merge latency hides under the TLP of still-running flash blocks.
__global__ __launch_bounds__(256) void flash_kernel(
        const unsigned short* __restrict__ qws, const unsigned short* __restrict__ kws,
        const unsigned short* __restrict__ vtws, const int* __restrict__ pmask,
        unsigned short* __restrict__ pO, float* __restrict__ pml,
        int* __restrict__ cnt, float* __restrict__ out) {
    __shared__ __align__(16) unsigned short Kt0[4096], Kt1[4096];
    __shared__ __align__(16) unsigned short Vt0[4096], Vt1[4096];
    __shared__ __align__(16) unsigned short Ps[4][1152];  // per-wave P [q16][kv 64+8]
    __shared__ __align__(16) float Bs[256];               // bias for <=4 iters
    __shared__ int lastf;

    const int t = threadIdx.x, blk = blockIdx.x;
    const int b = blk / 144, cid = blk - b * 144;
    // decode cid -> (qt, chunk): group g starts at 2g(g+1), spans 4(g+1)
    int g = 0;
    while (cid >= 2 * (g + 1) * (g + 2)) ++g;   // <=7 iters, block-uniform
    const int off = cid - 2 * g * (g + 1);
    const int qi = off / (g + 1);
    const int chunk = off - qi * (g + 1);
    const int qt = 4 * g + qi;
    const int jbeg = chunk * 4;
    int je = jbeg + 4; if (je > qt + 1) je = qt + 1;
    const int jend = je;
    const int niter = jend - jbeg;              // 1..4

    const int lane = t & 63, w = t >> 6;
    const int quad = lane >> 4, c = lane & 15;

    // staging geometry: instrs i0=2w, i1=2w+1 of 8; row = i*8 + (lane>>3)
    const int srow = lane >> 3, scb = (lane & 7) ^ srow;
    const unsigned short* kg0 = kws + (size_t)(b * TT + 2 * w * 8 + srow) * HS + scb * 8;
    const unsigned short* kg1 = kg0 + (size_t)8 * HS;
    const unsigned short* vg0 = vtws + (size_t)(b * 64 + 2 * w * 8 + srow) * TT + scb * 8;
    const unsigned short* vg1 = vg0 + (size_t)8 * TT;

#define FSTAGE(KD, VD, kv) \
    glds16(kg0 + (size_t)(kv) * HS, &KD[(2 * w + 0) * 512]); \
    glds16(kg1 + (size_t)(kv) * HS, &KD[(2 * w + 1) * 512]); \
    glds16(vg0 + (kv), &VD[(2 * w + 0) * 512]); \
    glds16(vg1 + (kv), &VD[(2 * w + 1) * 512]);

    // Q B-frag (n = qrow = c)
    bf16x8 qf[2];
#pragma unroll
    for (int kk = 0; kk < 2; ++kk)
        qf[kk] = ld_bf8(qws + (size_t)(b * TT + qt * 64 + w * 16 + c) * HS + kk * 32 + quad * 8);

    // fused bias: pad mask ints -> additive float bias in LDS
    {
        int bi = t * 4;
        if (bi < niter * 64) {
            i32x4 pmv = *(const i32x4*)(pmask + b * TT + jbeg * 64 + bi);
            f32x4 bvv;
#pragma unroll
            for (int j = 0; j < 4; ++j) bvv[j] = pmv[j] ? 0.0f : -1e30f;
            *(f32x4*)&Bs[bi] = bvv;
        }
    }

    // prologue: stage iter jbeg into buffer 0 (4 glds/wave in flight)
    FSTAGE(Kt0, Vt0, jbeg * 64)
    LGKM_BARRIER();   // Bs visible; glds drained by first VM0_BARRIER

    f32x4 o[4] = {};
    float m_run = -1e30f, l_run = 0.0f;
    const int ck7 = c & 7;

#define FITER(u, KT, VT, KD, VD) \
    if (j0 + (u) < jend) { \
        const int j = j0 + (u); \
        VM0_BARRIER(); \
        { int jn = j + 1; if (jn > jend - 1) jn = jend - 1; \
          FSTAGE(KD, VD, jn * 64) } \
        f32x4 bv[4]; \
        _Pragma("unroll") for (int nt = 0; nt < 4; ++nt) \
            bv[nt] = *(const f32x4*)&Bs[(j - jbeg) * 64 + nt * 16 + quad * 4]; \
        f32x4 s4[4] = {}; \
        _Pragma("unroll") for (int kk = 0; kk < 2; ++kk) \
        _Pragma("unroll") for (int nt = 0; nt < 4; ++nt) { \
            bf16x8 ka = ld_bf8(&KT[(nt * 16 + c) * 64 + (((kk * 4 + quad) ^ ck7) * 8)]); \
            s4[nt] = MFMA(ka, qf[kk], s4[nt]); } \
        if (j == qt) { \
            const int qrl = w * 16 + c; \
            _Pragma("unroll") for (int nt = 0; nt < 4; ++nt) \
            _Pragma("unroll") for (int r = 0; r < 4; ++r) { \
                int kvl = nt * 16 + quad * 4 + r; \
                s4[nt][r] = (kvl > qrl) ? -1e30f : (s4[nt][r] + bv[nt][r]); } \
        } else { \
            _Pragma("unroll") for (int nt = 0; nt < 4; ++nt) \
            _Pragma("unroll") for (int r = 0; r < 4; ++r) s4[nt][r] += bv[nt][r]; } \
        float mx = s4[0][0]; \
        _Pragma("unroll") for (int nt = 0; nt < 4; ++nt) \
        _Pragma("unroll") for (int r = 0; r < 4; ++r) mx = fmaxf(mx, s4[nt][r]); \
        mx = fmaxf(mx, __shfl_xor(mx, 16, 64)); \
        mx = fmaxf(mx, __shfl_xor(mx, 32, 64)); \
        float mnew = fmaxf(m_run, mx); \
        float al = exp2f(m_run - mnew); \
        m_run = mnew; \
        _Pragma("unroll") for (int nt = 0; nt < 4; ++nt) \
        _Pragma("unroll") for (int r = 0; r < 4; ++r) s4[nt][r] = exp2f(s4[nt][r] - mnew); \
        float rs = 0.0f; \
        _Pragma("unroll") for (int nt = 0; nt < 4; ++nt) \
            rs += (s4[nt][0] + s4[nt][1]) + (s4[nt][2] + s4[nt][3]); \
        rs += __shfl_xor(rs, 16, 64); \
        rs += __shfl_xor(rs, 32, 64); \
        l_run = l_run * al + rs; \
        _Pragma("unroll") for (int ht = 0; ht < 4; ++ht) \
        _Pragma("unroll") for (int r = 0; r < 4; ++r) o[ht][r] *= al; \
        _Pragma("unroll") for (int nt = 0; nt < 4; ++nt) { \
            u16x4 pk; \
            _Pragma("unroll") for (int r = 0; r < 4; ++r) pk[r] = cvt_bf16(s4[nt][r]); \
            *(u16x4*)&Ps[w][c * 72 + nt * 16 + quad * 4] = pk; } \
        bf16x8 p0 = ld_bf8(&Ps[w][c * 72 + quad * 8]); \
        bf16x8 p1 = ld_bf8(&Ps[w][c * 72 + 32 + quad * 8]); \
        _Pragma("unroll") for (int kk = 0; kk < 2; ++kk) { \
            bf16x8 pa = kk ? p1 : p0; \
            _Pragma("unroll") for (int ht = 0; ht < 4; ++ht) { \
                bf16x8 va = ld_bf8(&VT[(ht * 16 + c) * 64 + (((kk * 4 + quad) ^ ck7) * 8)]); \
                o[ht] = MFMA(va, pa, o[ht]); } } \
    }

    for (int j0 = jbeg; j0 < jend; j0 += 2) {
        FITER(0, Kt0, Vt0, Kt1, Vt1)
        FITER(1, Kt1, Vt1, Kt0, Vt0)
    }
#undef FITER
#undef FSTAGE

    VM_DRAIN();   // retire tail glds before LDS dealloc at endpgm

    // ---- store partials: slot = blk; pO [slot][row 64][h 64] ----
    unsigned short* po = pO + (size_t)blk * 4096;
#pragma unroll
    for (int ht = 0; ht < 4; ++ht) {
        u16x4 pk;
#pragma unroll
        for (int r = 0; r < 4; ++r) pk[r] = cvt_bf16(o[ht][r]);
        *(u16x4*)(po + (w * 16 + c) * 64 + ht * 16 + quad * 4) = pk;
    }
    if (quad == 0) {
        pml[(size_t)blk * 128 + (w * 16 + c) * 2] = m_run;
        pml[(size_t)blk * 128 + (w * 16 + c) * 2 + 1] = l_run;
    }

    // ---- fused combine: last finishing chunk merges its (b,qt) ----
    __threadfence();                       // release partial stores device-wide
    if (t == 0) {
        int old = atomicAdd(cnt + (b * 32 + qt), 1);
        lastf = (old == g);                // nc-1 == g
    }
    __syncthreads();
    if (!lastf) return;
    __threadfence();                       // acquire: invalidate before reads

    const int nc = g + 1;                  // 1..8 chunks, block-uniform
    const int s0 = b * 144 + 2 * g * (g + 1) + (qt - 4 * g) * (g + 1);
    const int h = t & 63, rg0 = t >> 6;
    for (int i = 0; i < 16; ++i) {
        const int row = rg0 + i * 4;
        float m_[8], l_[8], o_[8];
#pragma unroll
        for (int s = 0; s < 8; ++s) {
            const int slot = s0 + (s < nc ? s : 0);
            const float2 ml = *(const float2*)(pml + (size_t)slot * 128 + row * 2);
            const float ov = bf2f(pO[(size_t)slot * 4096 + row * 64 + h]);
            m_[s] = (s < nc) ? ml.x : -3.0e38f;
            l_[s] = (s < nc) ? ml.y : 0.0f;
            o_[s] = (s < nc) ? ov : 0.0f;
        }
        float M = m_[0];
#pragma unroll
        for (int s = 1; s < 8; ++s) M = fmaxf(M, m_[s]);
        float num = 0.0f, den = 0.0f;
#pragma unroll
        for (int s = 0; s < 8; ++s) {
            const float ww = exp2f(m_[s] - M);   // invalid slots -> 0
            num += o_[s] * ww;
            den += l_[s] * ww;
        }
        out[(size_t)(b * TT + qt * 64 + row) * HS + h] = num / den;
    }
}

extern "C" void kernel_launch(void* const* d_in, const int* in_sizes, int n_in,
                              void* d_out, int out_size, void* d_ws, size_t ws_size,
                              hipStream_t stream) {
    const float* x  = (const float*)d_in[0];
    const int* pm   = (const int*)d_in[1];
    const float* Wq = (const float*)d_in[2];
    const float* Wk = (const float*)d_in[3];
    const float* Wv = (const float*)d_in[4];
    float* out = (float*)d_out;

    unsigned short* wsu  = (unsigned short*)d_ws;
    unsigned short* wbt  = wsu + WBT_E;
    unsigned short* qws  = wsu + Q_E;
    unsigned short* kws  = wsu + K_E;
    unsigned short* vtws = wsu + VT_E;
    unsigned short* pO   = wsu + PO_E;
    float* pml           = (float*)(wsu + PML_E);
    int* cnt             = (int*)(wsu + CNT_E);

    wconv_kernel<<<48, 256, 0, stream>>>(Wq, Wk, Wv, wbt);
    proj_kernel<<<256, 512, 0, stream>>>(x, wbt, qws, kws, vtws, cnt);
    flash_kernel<<<1152, 256, 0, stream>>>(qws, kws, vtws, pm, pO, pml, cnt, out);
}

// Round 11
// 152.748 us; speedup vs baseline: 2.2698x; 2.2698x over previous
//
#include <hip/hip_runtime.h>

#define DEV static __device__ __forceinline__

typedef float f32x4 __attribute__((ext_vector_type(4)));
typedef int i32x4 __attribute__((ext_vector_type(4)));
typedef __bf16 bf16x8 __attribute__((ext_vector_type(8)));
typedef unsigned short u16x8 __attribute__((ext_vector_type(8)));
typedef unsigned short u16x4 __attribute__((ext_vector_type(4)));

#define MFMA(a, b, c) __builtin_amdgcn_mfma_f32_16x16x32_bf16((a), (b), (c), 0, 0, 0)

// fine-grained barriers: counted vmcnt (never a just-issued drain) + s_barrier.
#define WAIT5_BARRIER() asm volatile("s_waitcnt vmcnt(5)\n\ts_barrier" ::: "memory")
#define VM0_BARRIER()   asm volatile("s_waitcnt vmcnt(0)\n\ts_barrier" ::: "memory")
#define LGKM_BARRIER()  asm volatile("s_waitcnt lgkmcnt(0)\n\ts_barrier" ::: "memory")
#define VM_DRAIN()      asm volatile("s_waitcnt vmcnt(0)" ::: "memory")

// B=8, T=2048, C=1024, H=64
#define TT 2048
#define CE 1024
#define HS 64

// ws layout (ushort elements unless noted). ~16.8 MB of a 256 MiB arena.
#define WBT_E 0                   // [3][64 n][1024 k] bf16 (Wq scaled by log2e/32)
#define Q_E   196608              // [B*T][64] bf16
#define K_E   (Q_E + 1048576)
#define VT_E  (K_E + 1048576)     // [B][64 h][2048 t] bf16
#define PO_E  (VT_E + 1048576)    // [1152 slots][64 row][64 h] bf16 partial O
#define PML_E (PO_E + 4718592)    // float [1152][64 row][2] {m,l}
#define CNT_E (PML_E + 294912)    // int [256] chunk-completion counters

DEV unsigned short cvt_bf16(float f) {
    unsigned int u = __builtin_bit_cast(unsigned int, f);
    u += 0x7FFFu + ((u >> 16) & 1u);   // RNE (finite inputs)
    return (unsigned short)(u >> 16);
}

DEV float bf2f(unsigned short v) {
    unsigned int u = ((unsigned int)v) << 16;
    return __builtin_bit_cast(float, u);
}

DEV bf16x8 ld_bf8(const unsigned short* p) {
    union { u16x8 u; bf16x8 b; } v;
    v.u = *(const u16x8*)p;
    return v.b;
}

DEV bf16x8 as_bf8(u16x8 u) {
    union { u16x8 u; bf16x8 b; } v;
    v.u = u;
    return v.b;
}

// agent(device)-scope coherent access: compiler emits sc-flagged ops (bypass
// stale local L2, no cache-wide flush) AND owns the data dependency, so the
// waitcnt before use is correct (rule-#18-safe, unlike inline-asm loads).
DEV void st_agent_b64(void* p, unsigned long long v) {
    __hip_atomic_store((unsigned long long*)p, v, __ATOMIC_RELAXED,
                       __HIP_MEMORY_SCOPE_AGENT);
}
DEV unsigned long long ld_agent_b64(const void* p) {
    return __hip_atomic_load((const unsigned long long*)p, __ATOMIC_RELAXED,
                             __HIP_MEMORY_SCOPE_AGENT);
}
DEV unsigned short ld_agent_u16(const unsigned short* p) {
    return __hip_atomic_load(p, __ATOMIC_RELAXED, __HIP_MEMORY_SCOPE_AGENT);
}

// async global->LDS, 16B/lane; LDS dst is WAVE-UNIFORM base (+lane*16 by HW)
DEV void glds16(const void* g, void* l) {
    __builtin_amdgcn_global_load_lds(
        (const __attribute__((address_space(1))) void*)g,
        (__attribute__((address_space(3))) void*)l, 16, 0, 0);
}

// ---------------- kernel 1: W fp32 -> bf16 transposed [n][k] ----------------
__global__ __launch_bounds__(256) void wconv_kernel(
        const float* __restrict__ Wq, const float* __restrict__ Wk,
        const float* __restrict__ Wv, unsigned short* __restrict__ wbt) {
    __shared__ unsigned short Tr[64 * 72];
    const int blk = blockIdx.x;
    const int head = blk >> 4, kt = blk & 15;
    const int k0 = kt * 64;
    const float* W = (head == 0) ? Wq : ((head == 1) ? Wk : Wv);
    const float sc = (head == 0) ? 0.045084220027780106f : 1.0f;  // log2(e)/32
    const int t = threadIdx.x;
    const int rrow = t >> 4, c4 = (t & 15) * 4;
    for (int i = 0; i < 4; ++i) {
        int krow = rrow + i * 16;
        f32x4 f = *(const f32x4*)(W + (size_t)(k0 + krow) * 64 + c4);
        Tr[(c4 + 0) * 72 + krow] = cvt_bf16(f[0] * sc);
        Tr[(c4 + 1) * 72 + krow] = cvt_bf16(f[1] * sc);
        Tr[(c4 + 2) * 72 + krow] = cvt_bf16(f[2] * sc);
        Tr[(c4 + 3) * 72 + krow] = cvt_bf16(f[3] * sc);
    }
    __syncthreads();
    const int n = t >> 2, off = (t & 3) * 16;
    u16x8 a0 = *(const u16x8*)&Tr[n * 72 + off];
    u16x8 a1 = *(const u16x8*)&Tr[n * 72 + off + 8];
    unsigned short* dst = wbt + head * 65536 + n * 1024 + k0 + off;
    *(u16x8*)dst = a0;
    *(u16x8*)(dst + 8) = a1;
}

// ---------------- kernel 2: projection q,k = x@W; v transposed -> vt --------
// Big-slot structure (round-3): 256 blocks (1/CU) x 8 waves; block tile
// 64 rows x 192 cols, K-step 64, 16 slots. 40 glds/slot = uniform 5/wave,
// 3 LDS buffers (120 KB), depth-2 ring, vmcnt(5)+barrier. Also zeroes the
// flash chunk counters (kernel-boundary makes them visible to flash).
__global__ __launch_bounds__(512, 2) void proj_kernel(
        const float* __restrict__ x, const unsigned short* __restrict__ wbt,
        unsigned short* __restrict__ qws, unsigned short* __restrict__ kws,
        unsigned short* __restrict__ vtws, int* __restrict__ cnt) {
    __shared__ __align__(16) float Xt0[4096], Xt1[4096], Xt2[4096];          // 3x16 KB
    __shared__ __align__(16) unsigned short Wt0[12288], Wt1[12288], Wt2[12288]; // 3x24 KB
    __shared__ __align__(16) unsigned short TT2[64 * 72];  // v-transpose scratch

    const int t = threadIdx.x;
    if (t == 0) cnt[blockIdx.x] = 0;            // 256 blocks, 256 counters
    const int lane = t & 63, w = t >> 6;        // w in 0..7
    const int quad = lane >> 4, c = lane & 15;
    const int wm = w & 1, wn = w >> 1;          // 32-row half, 48-col quarter
    const int t0 = blockIdx.x * 64;
    const int ck7 = c & 7;

    // ---- staging geometry (content chunk = phys chunk ^ (row&7 | col&7)) --
    const int sxr = lane >> 4;                         // row-in-group 0..3
    const int sxc0 = (lane & 15) ^ sxr;                // key (0*4+sxr)&7
    const int sxc1 = (lane & 15) ^ ((4 + sxr) & 7);    // key (4+sxr)&7
    const float* xg0 = x + (size_t)(t0 + w * 8 + 0 + sxr) * CE + sxc0 * 4;
    const float* xg1 = x + (size_t)(t0 + w * 8 + 4 + sxr) * CE + sxc1 * 4;
    const int swc = lane >> 3;                         // col-in-group 0..7
    const int swk = (lane & 7) ^ swc;                  // key = col&7 = swc
    const unsigned short* wg0 = wbt + (size_t)(w * 24 + 0 + swc) * 1024 + swk * 8;
    const unsigned short* wg1 = wbt + (size_t)(w * 24 + 8 + swc) * 1024 + swk * 8;
    const unsigned short* wg2 = wbt + (size_t)(w * 24 + 16 + swc) * 1024 + swk * 8;

#define PSTAGE(XD, WD, ks) { \
    const int kf = (ks) * 64; \
    glds16(xg0 + kf, &XD[(w * 8 + 0) * 64]); \
    glds16(xg1 + kf, &XD[(w * 8 + 4) * 64]); \
    glds16(wg0 + kf, &WD[(w * 24 + 0) * 64]); \
    glds16(wg1 + kf, &WD[(w * 24 + 8) * 64]); \
    glds16(wg2 + kf, &WD[(w * 24 + 16) * 64]); }

    f32x4 acc[2][3] = {};

    PSTAGE(Xt0, Wt0, 0)
    PSTAGE(Xt1, Wt1, 1)

#define PITER(step, XT, WT, XD, WD) { \
    WAIT5_BARRIER(); \
    bf16x8 af[2][2]; \
    _Pragma("unroll") for (int rf = 0; rf < 2; ++rf) \
    _Pragma("unroll") for (int kk = 0; kk < 2; ++kk) { \
        const int row = wm * 32 + rf * 16 + c; \
        const int lc = kk * 8 + quad * 2; \
        f32x4 v0 = *(const f32x4*)&XT[row * 64 + ((lc ^ ck7) * 4)]; \
        f32x4 v1 = *(const f32x4*)&XT[row * 64 + (((lc + 1) ^ ck7) * 4)]; \
        u16x8 ap; \
        _Pragma("unroll") for (int j = 0; j < 4; ++j) { \
            ap[j] = cvt_bf16(v0[j]); ap[4 + j] = cvt_bf16(v1[j]); } \
        af[rf][kk] = as_bf8(ap); \
    } \
    _Pragma("unroll") for (int nt = 0; nt < 3; ++nt) \
    _Pragma("unroll") for (int kk = 0; kk < 2; ++kk) { \
        const int col = wn * 48 + nt * 16 + c; \
        bf16x8 bb = ld_bf8(&WT[col * 64 + (((kk * 4 + quad) ^ ck7) * 8)]); \
        acc[0][nt] = MFMA(af[0][kk], bb, acc[0][nt]); \
        acc[1][nt] = MFMA(af[1][kk], bb, acc[1][nt]); \
    } \
    PSTAGE(XD, WD, (((step) + 2) & 15)) }

    for (int s = 0; s < 15; s += 3) {
        PITER(s + 0, Xt0, Wt0, Xt2, Wt2)
        PITER(s + 1, Xt1, Wt1, Xt0, Wt0)
        PITER(s + 2, Xt2, Wt2, Xt1, Wt1)
    }
    PITER(15, Xt0, Wt0, Xt2, Wt2)   // tail: stages dummy (slice wraps to 1)
#undef PITER
#undef PSTAGE

    // epilogue: q,k direct; v transposed via LDS (64 h x 64 t, stride 72)
#pragma unroll
    for (int rf = 0; rf < 2; ++rf) {
#pragma unroll
        for (int nt = 0; nt < 3; ++nt) {
            int col = wn * 48 + nt * 16 + c;
            f32x4 a = acc[rf][nt];
#pragma unroll
            for (int r4 = 0; r4 < 4; ++r4) {
                int row = wm * 32 + rf * 16 + quad * 4 + r4;
                size_t tg = (size_t)(t0 + row);
                unsigned short hv = cvt_bf16(a[r4]);
                if (col < 64)       qws[tg * HS + col] = hv;
                else if (col < 128) kws[tg * HS + col - 64] = hv;
                else                TT2[(col - 128) * 72 + row] = hv;
            }
        }
    }
    __syncthreads();   // full drain: also retires the tail dummy glds
    {
        int h = t >> 3, off = (t & 7) * 8;
        u16x8 v = *(const u16x8*)&TT2[h * 72 + off];
        int b = t0 >> 11, tl0 = t0 & 2047;
        *(u16x8*)(vtws + (size_t)(b * 64 + h) * TT + tl0 + off) = v;
    }
}

// ---------------- kernel 3: flash + fused combine (agent-scope, no fence) --
// 1152 blocks = 8 b x 144 balanced 4-tile chunks (round-7 structure).
// Partials stored with agent-scope relaxed atomics (sc-flagged, no L2 flush)
// -> vmcnt(0) drain -> atomicAdd on cnt[b*32+qt]. Last finisher (old==g)
// merges with agent-scope loads (compiler-managed dependency: no rule-#18
// inline-asm register hazard, which NaN'd round 10; no __threadfence, which
// 10x'd round 9). Merge latency hides under still-running flash blocks.
__global__ __launch_bounds__(256) void flash_kernel(
        const unsigned short* __restrict__ qws, const unsigned short* __restrict__ kws,
        const unsigned short* __restrict__ vtws, const int* __restrict__ pmask,
        unsigned short* __restrict__ pO, float* __restrict__ pml,
        int* __restrict__ cnt, float* __restrict__ out) {
    __shared__ __align__(16) unsigned short Kt0[4096], Kt1[4096];
    __shared__ __align__(16) unsigned short Vt0[4096], Vt1[4096];
    __shared__ __align__(16) unsigned short Ps[4][1152];  // per-wave P [q16][kv 64+8]
    __shared__ __align__(16) float Bs[256];               // bias for <=4 iters
    __shared__ int lastf;

    const int t = threadIdx.x, blk = blockIdx.x;
    const int b = blk / 144, cid = blk - b * 144;
    int g = 0;
    while (cid >= 2 * (g + 1) * (g + 2)) ++g;   // <=7 iters, block-uniform
    const int off = cid - 2 * g * (g + 1);
    const int qi = off / (g + 1);
    const int chunk = off - qi * (g + 1);
    const int qt = 4 * g + qi;
    const int jbeg = chunk * 4;
    int je = jbeg + 4; if (je > qt + 1) je = qt + 1;
    const int jend = je;
    const int niter = jend - jbeg;              // 1..4

    const int lane = t & 63, w = t >> 6;
    const int quad = lane >> 4, c = lane & 15;

    const int srow = lane >> 3, scb = (lane & 7) ^ srow;
    const unsigned short* kg0 = kws + (size_t)(b * TT + 2 * w * 8 + srow) * HS + scb * 8;
    const unsigned short* kg1 = kg0 + (size_t)8 * HS;
    const unsigned short* vg0 = vtws + (size_t)(b * 64 + 2 * w * 8 + srow) * TT + scb * 8;
    const unsigned short* vg1 = vg0 + (size_t)8 * TT;

#define FSTAGE(KD, VD, kv) \
    glds16(kg0 + (size_t)(kv) * HS, &KD[(2 * w + 0) * 512]); \
    glds16(kg1 + (size_t)(kv) * HS, &KD[(2 * w + 1) * 512]); \
    glds16(vg0 + (kv), &VD[(2 * w + 0) * 512]); \
    glds16(vg1 + (kv), &VD[(2 * w + 1) * 512]);

    // Q B-frag (n = qrow = c)
    bf16x8 qf[2];
#pragma unroll
    for (int kk = 0; kk < 2; ++kk)
        qf[kk] = ld_bf8(qws + (size_t)(b * TT + qt * 64 + w * 16 + c) * HS + kk * 32 + quad * 8);

    // fused bias: pad mask ints -> additive float bias in LDS
    {
        int bi = t * 4;
        if (bi < niter * 64) {
            i32x4 pmv = *(const i32x4*)(pmask + b * TT + jbeg * 64 + bi);
            f32x4 bvv;
#pragma unroll
            for (int j = 0; j < 4; ++j) bvv[j] = pmv[j] ? 0.0f : -1e30f;
            *(f32x4*)&Bs[bi] = bvv;
        }
    }

    // prologue: stage iter jbeg into buffer 0 (4 glds/wave in flight)
    FSTAGE(Kt0, Vt0, jbeg * 64)
    LGKM_BARRIER();   // Bs visible; glds drained by first VM0_BARRIER

    f32x4 o[4] = {};
    float m_run = -1e30f, l_run = 0.0f;
    const int ck7 = c & 7;

#define FITER(u, KT, VT, KD, VD) \
    if (j0 + (u) < jend) { \
        const int j = j0 + (u); \
        VM0_BARRIER(); \
        { int jn = j + 1; if (jn > jend - 1) jn = jend - 1; \
          FSTAGE(KD, VD, jn * 64) } \
        f32x4 bv[4]; \
        _Pragma("unroll") for (int nt = 0; nt < 4; ++nt) \
            bv[nt] = *(const f32x4*)&Bs[(j - jbeg) * 64 + nt * 16 + quad * 4]; \
        f32x4 s4[4] = {}; \
        _Pragma("unroll") for (int kk = 0; kk < 2; ++kk) \
        _Pragma("unroll") for (int nt = 0; nt < 4; ++nt) { \
            bf16x8 ka = ld_bf8(&KT[(nt * 16 + c) * 64 + (((kk * 4 + quad) ^ ck7) * 8)]); \
            s4[nt] = MFMA(ka, qf[kk], s4[nt]); } \
        if (j == qt) { \
            const int qrl = w * 16 + c; \
            _Pragma("unroll") for (int nt = 0; nt < 4; ++nt) \
            _Pragma("unroll") for (int r = 0; r < 4; ++r) { \
                int kvl = nt * 16 + quad * 4 + r; \
                s4[nt][r] = (kvl > qrl) ? -1e30f : (s4[nt][r] + bv[nt][r]); } \
        } else { \
            _Pragma("unroll") for (int nt = 0; nt < 4; ++nt) \
            _Pragma("unroll") for (int r = 0; r < 4; ++r) s4[nt][r] += bv[nt][r]; } \
        float mx = s4[0][0]; \
        _Pragma("unroll") for (int nt = 0; nt < 4; ++nt) \
        _Pragma("unroll") for (int r = 0; r < 4; ++r) mx = fmaxf(mx, s4[nt][r]); \
        mx = fmaxf(mx, __shfl_xor(mx, 16, 64)); \
        mx = fmaxf(mx, __shfl_xor(mx, 32, 64)); \
        float mnew = fmaxf(m_run, mx); \
        float al = exp2f(m_run - mnew); \
        m_run = mnew; \
        _Pragma("unroll") for (int nt = 0; nt < 4; ++nt) \
        _Pragma("unroll") for (int r = 0; r < 4; ++r) s4[nt][r] = exp2f(s4[nt][r] - mnew); \
        float rs = 0.0f; \
        _Pragma("unroll") for (int nt = 0; nt < 4; ++nt) \
            rs += (s4[nt][0] + s4[nt][1]) + (s4[nt][2] + s4[nt][3]); \
        rs += __shfl_xor(rs, 16, 64); \
        rs += __shfl_xor(rs, 32, 64); \
        l_run = l_run * al + rs; \
        _Pragma("unroll") for (int ht = 0; ht < 4; ++ht) \
        _Pragma("unroll") for (int r = 0; r < 4; ++r) o[ht][r] *= al; \
        _Pragma("unroll") for (int nt = 0; nt < 4; ++nt) { \
            u16x4 pk; \
            _Pragma("unroll") for (int r = 0; r < 4; ++r) pk[r] = cvt_bf16(s4[nt][r]); \
            *(u16x4*)&Ps[w][c * 72 + nt * 16 + quad * 4] = pk; } \
        bf16x8 p0 = ld_bf8(&Ps[w][c * 72 + quad * 8]); \
        bf16x8 p1 = ld_bf8(&Ps[w][c * 72 + 32 + quad * 8]); \
        _Pragma("unroll") for (int kk = 0; kk < 2; ++kk) { \
            bf16x8 pa = kk ? p1 : p0; \
            _Pragma("unroll") for (int ht = 0; ht < 4; ++ht) { \
                bf16x8 va = ld_bf8(&VT[(ht * 16 + c) * 64 + (((kk * 4 + quad) ^ ck7) * 8)]); \
                o[ht] = MFMA(va, pa, o[ht]); } } \
    }

    for (int j0 = jbeg; j0 < jend; j0 += 2) {
        FITER(0, Kt0, Vt0, Kt1, Vt1)
        FITER(1, Kt1, Vt1, Kt0, Vt0)
    }
#undef FITER
#undef FSTAGE

    VM_DRAIN();   // retire tail glds before stores / LDS dealloc

    // ---- store partials agent-coherent: slot = blk; pO [slot][64][64] ----
    unsigned short* po = pO + (size_t)blk * 4096;
#pragma unroll
    for (int ht = 0; ht < 4; ++ht) {
        u16x4 pk;
#pragma unroll
        for (int r = 0; r < 4; ++r) pk[r] = cvt_bf16(o[ht][r]);
        st_agent_b64(po + (w * 16 + c) * 64 + ht * 16 + quad * 4,
                     __builtin_bit_cast(unsigned long long, pk));
    }
    if (quad == 0) {
        float2 ml2; ml2.x = m_run; ml2.y = l_run;
        st_agent_b64(pml + (size_t)blk * 128 + (w * 16 + c) * 2,
                     __builtin_bit_cast(unsigned long long, ml2));
    }
    VM_DRAIN();   // partials at coherence point before the atomic

    if (t == 0) {
        int old = atomicAdd(cnt + (b * 32 + qt), 1);
        lastf = (old == g);                // nc-1 == g
    }
    __syncthreads();
    if (!lastf) return;

    // ---- fused combine: agent-scope loads, batched per row-iter ----
    const int nc = g + 1;                  // 1..8 chunks, block-uniform
    const int s0 = b * 144 + 2 * g * (g + 1) + (qt - 4 * g) * (g + 1);
    const int h = t & 63, rg0 = t >> 6;
    for (int i = 0; i < 16; ++i) {
        const int row = rg0 + i * 4;
        unsigned long long mlraw[8];
        unsigned short poraw[8];
#pragma unroll
        for (int s = 0; s < 8; ++s) {
            const int slot = s0 + (s < nc ? s : 0);
            mlraw[s] = ld_agent_b64(pml + (size_t)slot * 128 + row * 2);
            poraw[s] = ld_agent_u16(pO + (size_t)slot * 4096 + row * 64 + h);
        }
        float m_[8], l_[8], o_[8];
#pragma unroll
        for (int s = 0; s < 8; ++s) {
            const float2 ml = __builtin_bit_cast(float2, mlraw[s]);
            m_[s] = (s < nc) ? ml.x : -3.0e38f;
            l_[s] = (s < nc) ? ml.y : 0.0f;
            o_[s] = (s < nc) ? bf2f(poraw[s]) : 0.0f;
        }
        float M = m_[0];
#pragma unroll
        for (int s = 1; s < 8; ++s) M = fmaxf(M, m_[s]);
        float num = 0.0f, den = 0.0f;
#pragma unroll
        for (int s = 0; s < 8; ++s) {
            const float ww = exp2f(m_[s] - M);   // invalid slots -> 0
            num += o_[s] * ww;
            den += l_[s] * ww;
        }
        out[(size_t)(b * TT + qt * 64 + row) * HS + h] = num / den;
    }
}

extern "C" void kernel_launch(void* const* d_in, const int* in_sizes, int n_in,
                              void* d_out, int out_size, void* d_ws, size_t ws_size,
                              hipStream_t stream) {
    const float* x  = (const float*)d_in[0];
    const int* pm   = (const int*)d_in[1];
    const float* Wq = (const float*)d_in[2];
    const float* Wk = (const float*)d_in[3];
    const float* Wv = (const float*)d_in[4];
    float* out = (float*)d_out;

    unsigned short* wsu  = (unsigned short*)d_ws;
    unsigned short* wbt  = wsu + WBT_E;
    unsigned short* qws  = wsu + Q_E;
    unsigned short* kws  = wsu + K_E;
    unsigned short* vtws = wsu + VT_E;
    unsigned short* pO   = wsu + PO_E;
    float* pml           = (float*)(wsu + PML_E);
    int* cnt             = (int*)(wsu + CNT_E);

    wconv_kernel<<<48, 256, 0, stream>>>(Wq, Wk, Wv, wbt);
    proj_kernel<<<256, 512, 0, stream>>>(x, wbt, qws, kws, vtws, cnt);
    flash_kernel<<<1152, 256, 0, stream>>>(qws, kws, vtws, pm, pO, pml, cnt, out);
}

// Round 12
// 142.451 us; speedup vs baseline: 2.4339x; 1.0723x over previous
//
#include <hip/hip_runtime.h>

#define DEV static __device__ __forceinline__

typedef float f32x4 __attribute__((ext_vector_type(4)));
typedef int i32x4 __attribute__((ext_vector_type(4)));
typedef __bf16 bf16x8 __attribute__((ext_vector_type(8)));
typedef unsigned short u16x8 __attribute__((ext_vector_type(8)));
typedef unsigned short u16x4 __attribute__((ext_vector_type(4)));

#define MFMA(a, b, c) __builtin_amdgcn_mfma_f32_16x16x32_bf16((a), (b), (c), 0, 0, 0)

// fine-grained barriers: counted vmcnt (never a just-issued drain) + s_barrier.
#define PBAR()          asm volatile("s_waitcnt vmcnt(3) lgkmcnt(0)\n\ts_barrier" ::: "memory")
#define VM0_BARRIER()   asm volatile("s_waitcnt vmcnt(0)\n\ts_barrier" ::: "memory")
#define LGKM_BARRIER()  asm volatile("s_waitcnt lgkmcnt(0)\n\ts_barrier" ::: "memory")
#define VM_DRAIN()      asm volatile("s_waitcnt vmcnt(0)" ::: "memory")

// B=8, T=2048, C=1024, H=64
#define TT 2048
#define CE 1024
#define HS 64

// ws layout (ushort elements unless noted). ~16.7 MB of a 256 MiB arena.
#define WBT_E 0                   // [3][64 n][1024 k] bf16 (Wq scaled by log2e/32)
#define Q_E   196608              // [B*T][64] bf16
#define K_E   (Q_E + 1048576)
#define VT_E  (K_E + 1048576)     // [B][64 h][2048 t] bf16
#define PO_E  (VT_E + 1048576)    // [1152 slots][64 row][64 h] bf16 partial O
#define PML_E (PO_E + 4718592)    // float [1152][64 row][2] {m,l}

DEV unsigned short cvt_bf16(float f) {
    unsigned int u = __builtin_bit_cast(unsigned int, f);
    u += 0x7FFFu + ((u >> 16) & 1u);   // RNE (finite inputs)
    return (unsigned short)(u >> 16);
}

DEV float bf2f(unsigned short v) {
    unsigned int u = ((unsigned int)v) << 16;
    return __builtin_bit_cast(float, u);
}

DEV bf16x8 ld_bf8(const unsigned short* p) {
    union { u16x8 u; bf16x8 b; } v;
    v.u = *(const u16x8*)p;
    return v.b;
}

DEV bf16x8 as_bf8(u16x8 u) {
    union { u16x8 u; bf16x8 b; } v;
    v.u = u;
    return v.b;
}

// async global->LDS, 16B/lane; LDS dst is WAVE-UNIFORM base (+lane*16 by HW)
DEV void glds16(const void* g, void* l) {
    __builtin_amdgcn_global_load_lds(
        (const __attribute__((address_space(1))) void*)g,
        (__attribute__((address_space(3))) void*)l, 16, 0, 0);
}

// ---------------- kernel 1: W fp32 -> bf16 transposed [n][k] ----------------
__global__ __launch_bounds__(256) void wconv_kernel(
        const float* __restrict__ Wq, const float* __restrict__ Wk,
        const float* __restrict__ Wv, unsigned short* __restrict__ wbt) {
    __shared__ unsigned short Tr[64 * 72];
    const int blk = blockIdx.x;
    const int head = blk >> 4, kt = blk & 15;
    const int k0 = kt * 64;
    const float* W = (head == 0) ? Wq : ((head == 1) ? Wk : Wv);
    const float sc = (head == 0) ? 0.045084220027780106f : 1.0f;  // log2(e)/32
    const int t = threadIdx.x;
    const int rrow = t >> 4, c4 = (t & 15) * 4;
    for (int i = 0; i < 4; ++i) {
        int krow = rrow + i * 16;
        f32x4 f = *(const f32x4*)(W + (size_t)(k0 + krow) * 64 + c4);
        Tr[(c4 + 0) * 72 + krow] = cvt_bf16(f[0] * sc);
        Tr[(c4 + 1) * 72 + krow] = cvt_bf16(f[1] * sc);
        Tr[(c4 + 2) * 72 + krow] = cvt_bf16(f[2] * sc);
        Tr[(c4 + 3) * 72 + krow] = cvt_bf16(f[3] * sc);
    }
    __syncthreads();
    const int n = t >> 2, off = (t & 3) * 16;
    u16x8 a0 = *(const u16x8*)&Tr[n * 72 + off];
    u16x8 a1 = *(const u16x8*)&Tr[n * 72 + off + 8];
    unsigned short* dst = wbt + head * 65536 + n * 1024 + k0 + off;
    *(u16x8*)dst = a0;
    *(u16x8*)(dst + 8) = a1;
}

// ---------------- kernel 2: projection q,k = x@W; v transposed -> vt --------
// Split-pipe rewrite: the glds path saturates at ~10 B/cy/CU aggregate
// (R0/R2/R3 invariant), so only W (96 MB) stays on it (ring-3, vmcnt(3)
// barrier). x (64 MB) moves to the plain vector-load pipe: per slot each
// thread does 2 coalesced f32x4 loads (held 2 slots ahead in named reg
// pairs xA/xB), cvt->bf16, one ds_write_b128 into a pad-72 LDS tile
// (bank-clean, no swizzle). A-frags become 4 ds_read_b128 (cvts leave the
// hot loop). 256 blocks (1/CU) x 8 waves; 64 rows x 192 cols; K-step 64.
__global__ __launch_bounds__(512, 1) void proj_kernel(
        const float* __restrict__ x, const unsigned short* __restrict__ wbt,
        unsigned short* __restrict__ qws, unsigned short* __restrict__ kws,
        unsigned short* __restrict__ vtws) {
    __shared__ __align__(16) unsigned short Xt0[64 * 72], Xt1[64 * 72];      // bf16 x, pad 72
    __shared__ __align__(16) unsigned short Wt0[12288], Wt1[12288], Wt2[12288]; // 3x24 KB
    __shared__ __align__(16) unsigned short TT2[64 * 72];  // v-transpose scratch

    const int t = threadIdx.x;
    const int lane = t & 63, w = t >> 6;        // w in 0..7
    const int quad = lane >> 4, c = lane & 15;
    const int wm = w & 1, wn = w >> 1;          // 32-row half, 48-col quarter
    const int t0 = blockIdx.x * 64;
    const int ck7 = c & 7;

    // x vector-load geometry: thread t -> row xr = t>>3, 16B-chunk xc = t&7
    const int xr = t >> 3, xc = t & 7;
    const float* xg = x + (size_t)(t0 + xr) * CE + xc * 8;   // 8 floats/thread/slot
    // W glds geometry (unchanged, XOR content-swizzle keyed on col&7)
    const int swc = lane >> 3;                         // col-in-group 0..7
    const int swk = (lane & 7) ^ swc;                  // key = col&7 = swc
    const unsigned short* wg0 = wbt + (size_t)(w * 24 + 0 + swc) * 1024 + swk * 8;
    const unsigned short* wg1 = wbt + (size_t)(w * 24 + 8 + swc) * 1024 + swk * 8;
    const unsigned short* wg2 = wbt + (size_t)(w * 24 + 16 + swc) * 1024 + swk * 8;

#define WSTAGE(WD, ks) { \
    const int kf = (ks) * 64; \
    glds16(wg0 + kf, &WD[(w * 24 + 0) * 64]); \
    glds16(wg1 + kf, &WD[(w * 24 + 8) * 64]); \
    glds16(wg2 + kf, &WD[(w * 24 + 16) * 64]); }

    f32x4 acc[2][3] = {};
    f32x4 xA0, xA1, xB0, xB1;    // named x reg double-buffer (static indexing)

    // prologue: x loads FIRST (so consuming them keeps W glds in flight)
    f32x4 p0 = *(const f32x4*)(xg);          // x slot 0
    f32x4 p1 = *(const f32x4*)(xg + 4);
    xA0 = *(const f32x4*)(xg + 64);          // x slot 1 -> regA
    xA1 = *(const f32x4*)(xg + 68);
    WSTAGE(Wt0, 0)
    WSTAGE(Wt1, 1)
    {
        u16x8 xp;
#pragma unroll
        for (int j = 0; j < 4; ++j) { xp[j] = cvt_bf16(p0[j]); xp[4 + j] = cvt_bf16(p1[j]); }
        *(u16x8*)&Xt0[xr * 72 + xc * 8] = xp;
    }
    // no barrier: body 0's PBAR (vmcnt(3)+lgkmcnt(0)+s_barrier) covers W0 + Xt0

#define PITER(step, WT, WD, XT, XD, RL0, RL1, RC0, RC1) { \
    PBAR(); \
    { const int kn = ((step) + 2 > 15 ? 15 : (step) + 2) * 64; \
      RL0 = *(const f32x4*)(xg + kn); \
      RL1 = *(const f32x4*)(xg + kn + 4); } \
    bf16x8 af[2][2]; \
    _Pragma("unroll") for (int rf = 0; rf < 2; ++rf) \
    _Pragma("unroll") for (int kk = 0; kk < 2; ++kk) \
        af[rf][kk] = ld_bf8(&XT[(wm * 32 + rf * 16 + c) * 72 + (kk * 4 + quad) * 8]); \
    _Pragma("unroll") for (int nt = 0; nt < 3; ++nt) \
    _Pragma("unroll") for (int kk = 0; kk < 2; ++kk) { \
        const int col = wn * 48 + nt * 16 + c; \
        bf16x8 bb = ld_bf8(&WT[col * 64 + (((kk * 4 + quad) ^ ck7) * 8)]); \
        acc[0][nt] = MFMA(af[0][kk], bb, acc[0][nt]); \
        acc[1][nt] = MFMA(af[1][kk], bb, acc[1][nt]); } \
    { u16x8 xp; \
      _Pragma("unroll") for (int j = 0; j < 4; ++j) { \
          xp[j] = cvt_bf16(RC0[j]); xp[4 + j] = cvt_bf16(RC1[j]); } \
      *(u16x8*)&XD[xr * 72 + xc * 8] = xp; } \
    WSTAGE(WD, ((step) + 2 > 15 ? 15 : (step) + 2)) }

    for (int s = 0; s < 12; s += 6) {
        PITER(s + 0, Wt0, Wt2, Xt0, Xt1, xB0, xB1, xA0, xA1)
        PITER(s + 1, Wt1, Wt0, Xt1, Xt0, xA0, xA1, xB0, xB1)
        PITER(s + 2, Wt2, Wt1, Xt0, Xt1, xB0, xB1, xA0, xA1)
        PITER(s + 3, Wt0, Wt2, Xt1, Xt0, xA0, xA1, xB0, xB1)
        PITER(s + 4, Wt1, Wt0, Xt0, Xt1, xB0, xB1, xA0, xA1)
        PITER(s + 5, Wt2, Wt1, Xt1, Xt0, xA0, xA1, xB0, xB1)
    }
    PITER(12, Wt0, Wt2, Xt0, Xt1, xB0, xB1, xA0, xA1)
    PITER(13, Wt1, Wt0, Xt1, Xt0, xA0, xA1, xB0, xB1)
    PITER(14, Wt2, Wt1, Xt0, Xt1, xB0, xB1, xA0, xA1)
    PITER(15, Wt0, Wt2, Xt1, Xt0, xA0, xA1, xB0, xB1)
#undef PITER
#undef WSTAGE

    // epilogue: q,k direct; v transposed via LDS (64 h x 64 t, stride 72)
#pragma unroll
    for (int rf = 0; rf < 2; ++rf) {
#pragma unroll
        for (int nt = 0; nt < 3; ++nt) {
            int col = wn * 48 + nt * 16 + c;
            f32x4 a = acc[rf][nt];
#pragma unroll
            for (int r4 = 0; r4 < 4; ++r4) {
                int row = wm * 32 + rf * 16 + quad * 4 + r4;
                size_t tg = (size_t)(t0 + row);
                unsigned short hv = cvt_bf16(a[r4]);
                if (col < 64)       qws[tg * HS + col] = hv;
                else if (col < 128) kws[tg * HS + col - 64] = hv;
                else                TT2[(col - 128) * 72 + row] = hv;
            }
        }
    }
    __syncthreads();   // full drain: also retires the tail dummy glds
    {
        int h = t >> 3, off = (t & 7) * 8;
        u16x8 v = *(const u16x8*)&TT2[h * 72 + off];
        int b = t0 >> 11, tl0 = t0 & 2047;
        *(u16x8*)(vtws + (size_t)(b * 64 + h) * TT + tl0 + off) = v;
    }
}

// ---------------- kernel 3: flash, ring-2, balanced 4-tile chunks ----------
// (round-8 proven form) 1152 blocks = 8 b x 144 chunks; q-tiles [4g,4g+3]
// each own g+1 chunks. Ring-2 stage-at-top: per iter {vmcnt(0)+barrier
// (drains loads issued a FULL iteration ago), stage j+1 into opposite
// buffer, compute j}. LDS 43 KB -> 3 blocks/CU concurrent staging streams.
__global__ __launch_bounds__(256) void flash_kernel(
        const unsigned short* __restrict__ qws, const unsigned short* __restrict__ kws,
        const unsigned short* __restrict__ vtws, const int* __restrict__ pmask,
        unsigned short* __restrict__ pO, float* __restrict__ pml) {
    __shared__ __align__(16) unsigned short Kt0[4096], Kt1[4096];
    __shared__ __align__(16) unsigned short Vt0[4096], Vt1[4096];
    __shared__ __align__(16) unsigned short Ps[4][1152];  // per-wave P [q16][kv 64+8]
    __shared__ __align__(16) float Bs[256];               // bias for <=4 iters

    const int t = threadIdx.x, blk = blockIdx.x;
    const int b = blk / 144, cid = blk - b * 144;
    // decode cid -> (qt, chunk): group g starts at 2g(g+1), spans 4(g+1)
    int g = 0;
    while (cid >= 2 * (g + 1) * (g + 2)) ++g;   // <=7 iters, block-uniform
    const int off = cid - 2 * g * (g + 1);
    const int qi = off / (g + 1);
    const int chunk = off - qi * (g + 1);
    const int qt = 4 * g + qi;
    const int jbeg = chunk * 4;
    int je = jbeg + 4; if (je > qt + 1) je = qt + 1;
    const int jend = je;
    const int niter = jend - jbeg;              // 1..4

    const int lane = t & 63, w = t >> 6;
    const int quad = lane >> 4, c = lane & 15;

    // staging geometry: instrs i0=2w, i1=2w+1 of 8; row = i*8 + (lane>>3)
    const int srow = lane >> 3, scb = (lane & 7) ^ srow;
    const unsigned short* kg0 = kws + (size_t)(b * TT + 2 * w * 8 + srow) * HS + scb * 8;
    const unsigned short* kg1 = kg0 + (size_t)8 * HS;
    const unsigned short* vg0 = vtws + (size_t)(b * 64 + 2 * w * 8 + srow) * TT + scb * 8;
    const unsigned short* vg1 = vg0 + (size_t)8 * TT;

#define FSTAGE(KD, VD, kv) \
    glds16(kg0 + (size_t)(kv) * HS, &KD[(2 * w + 0) * 512]); \
    glds16(kg1 + (size_t)(kv) * HS, &KD[(2 * w + 1) * 512]); \
    glds16(vg0 + (kv), &VD[(2 * w + 0) * 512]); \
    glds16(vg1 + (kv), &VD[(2 * w + 1) * 512]);

    // Q B-frag (n = qrow = c)
    bf16x8 qf[2];
#pragma unroll
    for (int kk = 0; kk < 2; ++kk)
        qf[kk] = ld_bf8(qws + (size_t)(b * TT + qt * 64 + w * 16 + c) * HS + kk * 32 + quad * 8);

    // fused bias: pad mask ints -> additive float bias in LDS
    {
        int bi = t * 4;
        if (bi < niter * 64) {
            i32x4 pmv = *(const i32x4*)(pmask + b * TT + jbeg * 64 + bi);
            f32x4 bvv;
#pragma unroll
            for (int j = 0; j < 4; ++j) bvv[j] = pmv[j] ? 0.0f : -1e30f;
            *(f32x4*)&Bs[bi] = bvv;
        }
    }

    // prologue: stage iter jbeg into buffer 0 (4 glds/wave in flight)
    FSTAGE(Kt0, Vt0, jbeg * 64)
    LGKM_BARRIER();   // Bs visible; glds drained by first VM0_BARRIER

    f32x4 o[4] = {};
    float m_run = -1e30f, l_run = 0.0f;
    const int ck7 = c & 7;

#define FITER(u, KT, VT, KD, VD) \
    if (j0 + (u) < jend) { \
        const int j = j0 + (u); \
        VM0_BARRIER(); \
        { int jn = j + 1; if (jn > jend - 1) jn = jend - 1; \
          FSTAGE(KD, VD, jn * 64) } \
        f32x4 bv[4]; \
        _Pragma("unroll") for (int nt = 0; nt < 4; ++nt) \
            bv[nt] = *(const f32x4*)&Bs[(j - jbeg) * 64 + nt * 16 + quad * 4]; \
        f32x4 s4[4] = {}; \
        _Pragma("unroll") for (int kk = 0; kk < 2; ++kk) \
        _Pragma("unroll") for (int nt = 0; nt < 4; ++nt) { \
            bf16x8 ka = ld_bf8(&KT[(nt * 16 + c) * 64 + (((kk * 4 + quad) ^ ck7) * 8)]); \
            s4[nt] = MFMA(ka, qf[kk], s4[nt]); } \
        if (j == qt) { \
            const int qrl = w * 16 + c; \
            _Pragma("unroll") for (int nt = 0; nt < 4; ++nt) \
            _Pragma("unroll") for (int r = 0; r < 4; ++r) { \
                int kvl = nt * 16 + quad * 4 + r; \
                s4[nt][r] = (kvl > qrl) ? -1e30f : (s4[nt][r] + bv[nt][r]); } \
        } else { \
            _Pragma("unroll") for (int nt = 0; nt < 4; ++nt) \
            _Pragma("unroll") for (int r = 0; r < 4; ++r) s4[nt][r] += bv[nt][r]; } \
        float mx = s4[0][0]; \
        _Pragma("unroll") for (int nt = 0; nt < 4; ++nt) \
        _Pragma("unroll") for (int r = 0; r < 4; ++r) mx = fmaxf(mx, s4[nt][r]); \
        mx = fmaxf(mx, __shfl_xor(mx, 16, 64)); \
        mx = fmaxf(mx, __shfl_xor(mx, 32, 64)); \
        float mnew = fmaxf(m_run, mx); \
        float al = exp2f(m_run - mnew); \
        m_run = mnew; \
        _Pragma("unroll") for (int nt = 0; nt < 4; ++nt) \
        _Pragma("unroll") for (int r = 0; r < 4; ++r) s4[nt][r] = exp2f(s4[nt][r] - mnew); \
        float rs = 0.0f; \
        _Pragma("unroll") for (int nt = 0; nt < 4; ++nt) \
            rs += (s4[nt][0] + s4[nt][1]) + (s4[nt][2] + s4[nt][3]); \
        rs += __shfl_xor(rs, 16, 64); \
        rs += __shfl_xor(rs, 32, 64); \
        l_run = l_run * al + rs; \
        _Pragma("unroll") for (int ht = 0; ht < 4; ++ht) \
        _Pragma("unroll") for (int r = 0; r < 4; ++r) o[ht][r] *= al; \
        _Pragma("unroll") for (int nt = 0; nt < 4; ++nt) { \
            u16x4 pk; \
            _Pragma("unroll") for (int r = 0; r < 4; ++r) pk[r] = cvt_bf16(s4[nt][r]); \
            *(u16x4*)&Ps[w][c * 72 + nt * 16 + quad * 4] = pk; } \
        bf16x8 p0 = ld_bf8(&Ps[w][c * 72 + quad * 8]); \
        bf16x8 p1 = ld_bf8(&Ps[w][c * 72 + 32 + quad * 8]); \
        _Pragma("unroll") for (int kk = 0; kk < 2; ++kk) { \
            bf16x8 pa = kk ? p1 : p0; \
            _Pragma("unroll") for (int ht = 0; ht < 4; ++ht) { \
                bf16x8 va = ld_bf8(&VT[(ht * 16 + c) * 64 + (((kk * 4 + quad) ^ ck7) * 8)]); \
                o[ht] = MFMA(va, pa, o[ht]); } } \
    }

    for (int j0 = jbeg; j0 < jend; j0 += 2) {
        FITER(0, Kt0, Vt0, Kt1, Vt1)
        FITER(1, Kt1, Vt1, Kt0, Vt0)
    }
#undef FITER
#undef FSTAGE

    VM_DRAIN();   // retire tail glds before LDS dealloc at endpgm

    // ---- store partials: slot = blk; pO [slot][row 64][h 64] ----
    unsigned short* po = pO + (size_t)blk * 4096;
#pragma unroll
    for (int ht = 0; ht < 4; ++ht) {
        u16x4 pk;
#pragma unroll
        for (int r = 0; r < 4; ++r) pk[r] = cvt_bf16(o[ht][r]);
        *(u16x4*)(po + (w * 16 + c) * 64 + ht * 16 + quad * 4) = pk;
    }
    if (quad == 0) {
        pml[(size_t)blk * 128 + (w * 16 + c) * 2] = m_run;
        pml[(size_t)blk * 128 + (w * 16 + c) * 2 + 1] = l_run;
    }
}

// ---------------- kernel 4: combine g+1 chunks, one thread per output -------
// (round-8 proven form) 4096 blocks x 256 thr = 1M threads; h = lane so
// qt/nc are wave-uniform. All <=8 chunk loads issued as a fully-unrolled
// predicated batch (static register indexing, 16 independent loads in
// flight) -> single latency exposure, hidden by TLP. One pass.
__global__ __launch_bounds__(256) void combine_kernel(
        const unsigned short* __restrict__ pO, const float* __restrict__ pml,
        float* __restrict__ out) {
    const int gid = blockIdx.x * 256 + threadIdx.x;
    const int h = gid & 63;
    const int grow = gid >> 6;            // global row 0..16383
    const int b = grow >> 11;
    const int rin = grow & 2047;
    const int qt = rin >> 6;
    const int row = rin & 63;
    const int g = qt >> 2;
    const int nc = g + 1;                 // 1..8 chunks, wave-uniform
    const int s0 = b * 144 + 2 * g * (g + 1) + (qt - 4 * g) * (g + 1);

    float m_[8], l_[8], o_[8];
#pragma unroll
    for (int s = 0; s < 8; ++s) {
        const int slot = s0 + (s < nc ? s : 0);   // clamp: predicated out below
        const float2 ml = *(const float2*)(pml + (size_t)slot * 128 + row * 2);
        const float ov = bf2f(pO[(size_t)slot * 4096 + row * 64 + h]);
        m_[s] = (s < nc) ? ml.x : -3.0e38f;
        l_[s] = (s < nc) ? ml.y : 0.0f;
        o_[s] = (s < nc) ? ov : 0.0f;
    }
    float M = m_[0];
#pragma unroll
    for (int s = 1; s < 8; ++s) M = fmaxf(M, m_[s]);
    float num = 0.0f, den = 0.0f;
#pragma unroll
    for (int s = 0; s < 8; ++s) {
        const float ww = exp2f(m_[s] - M);    // invalid slots -> exp2(-huge)=0
        num += o_[s] * ww;
        den += l_[s] * ww;
    }
    out[(size_t)(b * TT + qt * 64 + row) * HS + h] = num / den;
}

extern "C" void kernel_launch(void* const* d_in, const int* in_sizes, int n_in,
                              void* d_out, int out_size, void* d_ws, size_t ws_size,
                              hipStream_t stream) {
    const float* x  = (const float*)d_in[0];
    const int* pm   = (const int*)d_in[1];
    const float* Wq = (const float*)d_in[2];
    const float* Wk = (const float*)d_in[3];
    const float* Wv = (const float*)d_in[4];
    float* out = (float*)d_out;

    unsigned short* wsu  = (unsigned short*)d_ws;
    unsigned short* wbt  = wsu + WBT_E;
    unsigned short* qws  = wsu + Q_E;
    unsigned short* kws  = wsu + K_E;
    unsigned short* vtws = wsu + VT_E;
    unsigned short* pO   = wsu + PO_E;
    float* pml           = (float*)(wsu + PML_E);

    wconv_kernel<<<48, 256, 0, stream>>>(Wq, Wk, Wv, wbt);
    proj_kernel<<<256, 512, 0, stream>>>(x, wbt, qws, kws, vtws);
    flash_kernel<<<1152, 256, 0, stream>>>(qws, kws, vtws, pm, pO, pml);
    combine_kernel<<<4096, 256, 0, stream>>>(pO, pml, out);
}

// Round 13
// 139.254 us; speedup vs baseline: 2.4898x; 1.0230x over previous
//
#include <hip/hip_runtime.h>

#define DEV static __device__ __forceinline__

typedef float f32x4 __attribute__((ext_vector_type(4)));
typedef int i32x4 __attribute__((ext_vector_type(4)));
typedef __bf16 bf16x8 __attribute__((ext_vector_type(8)));
typedef unsigned short u16x8 __attribute__((ext_vector_type(8)));
typedef unsigned short u16x4 __attribute__((ext_vector_type(4)));

#define MFMA(a, b, c) __builtin_amdgcn_mfma_f32_16x16x32_bf16((a), (b), (c), 0, 0, 0)

// fine-grained barriers: counted vmcnt (never a just-issued drain) + s_barrier.
#define WAIT5_BARRIER() asm volatile("s_waitcnt vmcnt(5)\n\ts_barrier" ::: "memory")
#define VM0_BARRIER()   asm volatile("s_waitcnt vmcnt(0)\n\ts_barrier" ::: "memory")
#define LGKM_BARRIER()  asm volatile("s_waitcnt lgkmcnt(0)\n\ts_barrier" ::: "memory")
#define VM_DRAIN()      asm volatile("s_waitcnt vmcnt(0)" ::: "memory")

// B=8, T=2048, C=1024, H=64
#define TT 2048
#define CE 1024
#define HS 64

// ws layout (ushort elements unless noted). Total ~16.7 MB; round-6 profile
// shows the harness poisons a 256 MiB workspace arena, so this is safe.
#define WBT_E 0                   // [3][64 n][1024 k] bf16 (Wq scaled by log2e/32)
#define Q_E   196608              // [B*T][64] bf16
#define K_E   (Q_E + 1048576)
#define VT_E  (K_E + 1048576)     // [B][64 h][2048 t] bf16
#define PO_E  (VT_E + 1048576)    // [1152 slots][64 row][64 h] bf16 partial O
#define PML_E (PO_E + 4718592)    // float [1152][64 row][2] {m,l}

DEV unsigned short cvt_bf16(float f) {
    unsigned int u = __builtin_bit_cast(unsigned int, f);
    u += 0x7FFFu + ((u >> 16) & 1u);   // RNE (finite inputs)
    return (unsigned short)(u >> 16);
}

DEV float bf2f(unsigned short v) {
    unsigned int u = ((unsigned int)v) << 16;
    return __builtin_bit_cast(float, u);
}

DEV bf16x8 ld_bf8(const unsigned short* p) {
    union { u16x8 u; bf16x8 b; } v;
    v.u = *(const u16x8*)p;
    return v.b;
}

DEV bf16x8 as_bf8(u16x8 u) {
    union { u16x8 u; bf16x8 b; } v;
    v.u = u;
    return v.b;
}

// async global->LDS, 16B/lane; LDS dst is WAVE-UNIFORM base (+lane*16 by HW)
DEV void glds16(const void* g, void* l) {
    __builtin_amdgcn_global_load_lds(
        (const __attribute__((address_space(1))) void*)g,
        (__attribute__((address_space(3))) void*)l, 16, 0, 0);
}

// ---------------- kernel 1: W fp32 -> bf16 transposed [n][k] ----------------
__global__ __launch_bounds__(256) void wconv_kernel(
        const float* __restrict__ Wq, const float* __restrict__ Wk,
        const float* __restrict__ Wv, unsigned short* __restrict__ wbt) {
    __shared__ unsigned short Tr[64 * 72];
    const int blk = blockIdx.x;
    const int head = blk >> 4, kt = blk & 15;
    const int k0 = kt * 64;
    const float* W = (head == 0) ? Wq : ((head == 1) ? Wk : Wv);
    const float sc = (head == 0) ? 0.045084220027780106f : 1.0f;  // log2(e)/32
    const int t = threadIdx.x;
    const int rrow = t >> 4, c4 = (t & 15) * 4;
    for (int i = 0; i < 4; ++i) {
        int krow = rrow + i * 16;
        f32x4 f = *(const f32x4*)(W + (size_t)(k0 + krow) * 64 + c4);
        Tr[(c4 + 0) * 72 + krow] = cvt_bf16(f[0] * sc);
        Tr[(c4 + 1) * 72 + krow] = cvt_bf16(f[1] * sc);
        Tr[(c4 + 2) * 72 + krow] = cvt_bf16(f[2] * sc);
        Tr[(c4 + 3) * 72 + krow] = cvt_bf16(f[3] * sc);
    }
    __syncthreads();
    const int n = t >> 2, off = (t & 3) * 16;
    u16x8 a0 = *(const u16x8*)&Tr[n * 72 + off];
    u16x8 a1 = *(const u16x8*)&Tr[n * 72 + off + 8];
    unsigned short* dst = wbt + head * 65536 + n * 1024 + k0 + off;
    *(u16x8*)dst = a0;
    *(u16x8*)(dst + 8) = a1;
}

// ---------------- kernel 2: projection q,k = x@W; v transposed -> vt --------
// Big-slot structure (round-3): 256 blocks (1/CU) x 8 waves; block tile
// 64 rows x 192 cols, K-step 64, 16 slots. 40 glds/slot = uniform 5/wave,
// 3 LDS buffers (120 KB), depth-2 ring, vmcnt(5)+barrier. At the measured
// device-wide ~6 TB/s glds aggregate wall: 160 MB staged -> ~27 us (min
// staged bytes for this op; split-pipe variant R12 was null).
__global__ __launch_bounds__(512, 2) void proj_kernel(
        const float* __restrict__ x, const unsigned short* __restrict__ wbt,
        unsigned short* __restrict__ qws, unsigned short* __restrict__ kws,
        unsigned short* __restrict__ vtws) {
    __shared__ __align__(16) float Xt0[4096], Xt1[4096], Xt2[4096];          // 3x16 KB
    __shared__ __align__(16) unsigned short Wt0[12288], Wt1[12288], Wt2[12288]; // 3x24 KB
    __shared__ __align__(16) unsigned short TT2[64 * 72];  // v-transpose scratch

    const int t = threadIdx.x;
    const int lane = t & 63, w = t >> 6;        // w in 0..7
    const int quad = lane >> 4, c = lane & 15;
    const int wm = w & 1, wn = w >> 1;          // 32-row half, 48-col quarter
    const int t0 = blockIdx.x * 64;
    const int ck7 = c & 7;

    // ---- staging geometry (content chunk = phys chunk ^ (row&7 | col&7)) --
    const int sxr = lane >> 4;                         // row-in-group 0..3
    const int sxc0 = (lane & 15) ^ sxr;                // key (0*4+sxr)&7
    const int sxc1 = (lane & 15) ^ ((4 + sxr) & 7);    // key (4+sxr)&7
    const float* xg0 = x + (size_t)(t0 + w * 8 + 0 + sxr) * CE + sxc0 * 4;
    const float* xg1 = x + (size_t)(t0 + w * 8 + 4 + sxr) * CE + sxc1 * 4;
    const int swc = lane >> 3;                         // col-in-group 0..7
    const int swk = (lane & 7) ^ swc;                  // key = col&7 = swc
    const unsigned short* wg0 = wbt + (size_t)(w * 24 + 0 + swc) * 1024 + swk * 8;
    const unsigned short* wg1 = wbt + (size_t)(w * 24 + 8 + swc) * 1024 + swk * 8;
    const unsigned short* wg2 = wbt + (size_t)(w * 24 + 16 + swc) * 1024 + swk * 8;

#define PSTAGE(XD, WD, ks) { \
    const int kf = (ks) * 64; \
    glds16(xg0 + kf, &XD[(w * 8 + 0) * 64]); \
    glds16(xg1 + kf, &XD[(w * 8 + 4) * 64]); \
    glds16(wg0 + kf, &WD[(w * 24 + 0) * 64]); \
    glds16(wg1 + kf, &WD[(w * 24 + 8) * 64]); \
    glds16(wg2 + kf, &WD[(w * 24 + 16) * 64]); }

    f32x4 acc[2][3] = {};

    PSTAGE(Xt0, Wt0, 0)
    PSTAGE(Xt1, Wt1, 1)

#define PITER(step, XT, WT, XD, WD) { \
    WAIT5_BARRIER(); \
    bf16x8 af[2][2]; \
    _Pragma("unroll") for (int rf = 0; rf < 2; ++rf) \
    _Pragma("unroll") for (int kk = 0; kk < 2; ++kk) { \
        const int row = wm * 32 + rf * 16 + c; \
        const int lc = kk * 8 + quad * 2; \
        f32x4 v0 = *(const f32x4*)&XT[row * 64 + ((lc ^ ck7) * 4)]; \
        f32x4 v1 = *(const f32x4*)&XT[row * 64 + (((lc + 1) ^ ck7) * 4)]; \
        u16x8 ap; \
        _Pragma("unroll") for (int j = 0; j < 4; ++j) { \
            ap[j] = cvt_bf16(v0[j]); ap[4 + j] = cvt_bf16(v1[j]); } \
        af[rf][kk] = as_bf8(ap); \
    } \
    _Pragma("unroll") for (int nt = 0; nt < 3; ++nt) \
    _Pragma("unroll") for (int kk = 0; kk < 2; ++kk) { \
        const int col = wn * 48 + nt * 16 + c; \
        bf16x8 bb = ld_bf8(&WT[col * 64 + (((kk * 4 + quad) ^ ck7) * 8)]); \
        acc[0][nt] = MFMA(af[0][kk], bb, acc[0][nt]); \
        acc[1][nt] = MFMA(af[1][kk], bb, acc[1][nt]); \
    } \
    PSTAGE(XD, WD, (((step) + 2) & 15)) }

    for (int s = 0; s < 15; s += 3) {
        PITER(s + 0, Xt0, Wt0, Xt2, Wt2)
        PITER(s + 1, Xt1, Wt1, Xt0, Wt0)
        PITER(s + 2, Xt2, Wt2, Xt1, Wt1)
    }
    PITER(15, Xt0, Wt0, Xt2, Wt2)   // tail: stages dummy (slice wraps to 1)
#undef PITER
#undef PSTAGE

    // epilogue: q,k direct; v transposed via LDS (64 h x 64 t, stride 72)
#pragma unroll
    for (int rf = 0; rf < 2; ++rf) {
#pragma unroll
        for (int nt = 0; nt < 3; ++nt) {
            int col = wn * 48 + nt * 16 + c;
            f32x4 a = acc[rf][nt];
#pragma unroll
            for (int r4 = 0; r4 < 4; ++r4) {
                int row = wm * 32 + rf * 16 + quad * 4 + r4;
                size_t tg = (size_t)(t0 + row);
                unsigned short hv = cvt_bf16(a[r4]);
                if (col < 64)       qws[tg * HS + col] = hv;
                else if (col < 128) kws[tg * HS + col - 64] = hv;
                else                TT2[(col - 128) * 72 + row] = hv;
            }
        }
    }
    __syncthreads();   // full drain: also retires the tail dummy glds
    {
        int h = t >> 3, off = (t & 7) * 8;
        u16x8 v = *(const u16x8*)&TT2[h * 72 + off];
        int b = t0 >> 11, tl0 = t0 & 2047;
        *(u16x8*)(vtws + (size_t)(b * 64 + h) * TT + tl0 + off) = v;
    }
}

// ---------------- kernel 3: flash, ring-2, balanced 4-tile chunks ----------
// 1152 blocks = 8 b x 144 chunks. Chunk = up to 4 kv-tiles of one q-tile:
// q-tiles [4g, 4g+3] each own g+1 chunks (all non-empty). Block durations
// 1..4 iters -> balanced makespan; LDS 43 KB -> 3 blocks/CU concurrent
// staging streams. Ring-2 stage-at-top: per iter {vmcnt(0)+barrier (drains
// loads issued a FULL iteration ago), stage j+1 into opposite buffer,
// compute j}.
__global__ __launch_bounds__(256) void flash_kernel(
        const unsigned short* __restrict__ qws, const unsigned short* __restrict__ kws,
        const unsigned short* __restrict__ vtws, const int* __restrict__ pmask,
        unsigned short* __restrict__ pO, float* __restrict__ pml) {
    __shared__ __align__(16) unsigned short Kt0[4096], Kt1[4096];
    __shared__ __align__(16) unsigned short Vt0[4096], Vt1[4096];
    __shared__ __align__(16) unsigned short Ps[4][1152];  // per-wave P [q16][kv 64+8]
    __shared__ __align__(16) float Bs[256];               // bias for <=4 iters

    const int t = threadIdx.x, blk = blockIdx.x;
    const int b = blk / 144, cid = blk - b * 144;
    // decode cid -> (qt, chunk): group g starts at 2g(g+1), spans 4(g+1)
    int g = 0;
    while (cid >= 2 * (g + 1) * (g + 2)) ++g;   // <=7 iters, block-uniform
    const int off = cid - 2 * g * (g + 1);
    const int qi = off / (g + 1);
    const int chunk = off - qi * (g + 1);
    const int qt = 4 * g + qi;
    const int jbeg = chunk * 4;
    int je = jbeg + 4; if (je > qt + 1) je = qt + 1;
    const int jend = je;
    const int niter = jend - jbeg;              // 1..4

    const int lane = t & 63, w = t >> 6;
    const int quad = lane >> 4, c = lane & 15;

    // staging geometry: instrs i0=2w, i1=2w+1 of 8; row = i*8 + (lane>>3)
    const int srow = lane >> 3, scb = (lane & 7) ^ srow;
    const unsigned short* kg0 = kws + (size_t)(b * TT + 2 * w * 8 + srow) * HS + scb * 8;
    const unsigned short* kg1 = kg0 + (size_t)8 * HS;
    const unsigned short* vg0 = vtws + (size_t)(b * 64 + 2 * w * 8 + srow) * TT + scb * 8;
    const unsigned short* vg1 = vg0 + (size_t)8 * TT;

#define FSTAGE(KD, VD, kv) \
    glds16(kg0 + (size_t)(kv) * HS, &KD[(2 * w + 0) * 512]); \
    glds16(kg1 + (size_t)(kv) * HS, &KD[(2 * w + 1) * 512]); \
    glds16(vg0 + (kv), &VD[(2 * w + 0) * 512]); \
    glds16(vg1 + (kv), &VD[(2 * w + 1) * 512]);

    // Q B-frag (n = qrow = c)
    bf16x8 qf[2];
#pragma unroll
    for (int kk = 0; kk < 2; ++kk)
        qf[kk] = ld_bf8(qws + (size_t)(b * TT + qt * 64 + w * 16 + c) * HS + kk * 32 + quad * 8);

    // fused bias: pad mask ints -> additive float bias in LDS
    {
        int bi = t * 4;
        if (bi < niter * 64) {
            i32x4 pmv = *(const i32x4*)(pmask + b * TT + jbeg * 64 + bi);
            f32x4 bvv;
#pragma unroll
            for (int j = 0; j < 4; ++j) bvv[j] = pmv[j] ? 0.0f : -1e30f;
            *(f32x4*)&Bs[bi] = bvv;
        }
    }

    // prologue: stage iter jbeg into buffer 0 (4 glds/wave in flight)
    FSTAGE(Kt0, Vt0, jbeg * 64)
    LGKM_BARRIER();   // Bs visible; glds drained by first VM0_BARRIER

    f32x4 o[4] = {};
    float m_run = -1e30f, l_run = 0.0f;
    const int ck7 = c & 7;

#define FITER(u, KT, VT, KD, VD) \
    if (j0 + (u) < jend) { \
        const int j = j0 + (u); \
        VM0_BARRIER(); \
        { int jn = j + 1; if (jn > jend - 1) jn = jend - 1; \
          FSTAGE(KD, VD, jn * 64) } \
        f32x4 bv[4]; \
        _Pragma("unroll") for (int nt = 0; nt < 4; ++nt) \
            bv[nt] = *(const f32x4*)&Bs[(j - jbeg) * 64 + nt * 16 + quad * 4]; \
        f32x4 s4[4] = {}; \
        _Pragma("unroll") for (int kk = 0; kk < 2; ++kk) \
        _Pragma("unroll") for (int nt = 0; nt < 4; ++nt) { \
            bf16x8 ka = ld_bf8(&KT[(nt * 16 + c) * 64 + (((kk * 4 + quad) ^ ck7) * 8)]); \
            s4[nt] = MFMA(ka, qf[kk], s4[nt]); } \
        if (j == qt) { \
            const int qrl = w * 16 + c; \
            _Pragma("unroll") for (int nt = 0; nt < 4; ++nt) \
            _Pragma("unroll") for (int r = 0; r < 4; ++r) { \
                int kvl = nt * 16 + quad * 4 + r; \
                s4[nt][r] = (kvl > qrl) ? -1e30f : (s4[nt][r] + bv[nt][r]); } \
        } else { \
            _Pragma("unroll") for (int nt = 0; nt < 4; ++nt) \
            _Pragma("unroll") for (int r = 0; r < 4; ++r) s4[nt][r] += bv[nt][r]; } \
        float mx = s4[0][0]; \
        _Pragma("unroll") for (int nt = 0; nt < 4; ++nt) \
        _Pragma("unroll") for (int r = 0; r < 4; ++r) mx = fmaxf(mx, s4[nt][r]); \
        mx = fmaxf(mx, __shfl_xor(mx, 16, 64)); \
        mx = fmaxf(mx, __shfl_xor(mx, 32, 64)); \
        float mnew = fmaxf(m_run, mx); \
        float al = exp2f(m_run - mnew); \
        m_run = mnew; \
        _Pragma("unroll") for (int nt = 0; nt < 4; ++nt) \
        _Pragma("unroll") for (int r = 0; r < 4; ++r) s4[nt][r] = exp2f(s4[nt][r] - mnew); \
        float rs = 0.0f; \
        _Pragma("unroll") for (int nt = 0; nt < 4; ++nt) \
            rs += (s4[nt][0] + s4[nt][1]) + (s4[nt][2] + s4[nt][3]); \
        rs += __shfl_xor(rs, 16, 64); \
        rs += __shfl_xor(rs, 32, 64); \
        l_run = l_run * al + rs; \
        _Pragma("unroll") for (int ht = 0; ht < 4; ++ht) \
        _Pragma("unroll") for (int r = 0; r < 4; ++r) o[ht][r] *= al; \
        _Pragma("unroll") for (int nt = 0; nt < 4; ++nt) { \
            u16x4 pk; \
            _Pragma("unroll") for (int r = 0; r < 4; ++r) pk[r] = cvt_bf16(s4[nt][r]); \
            *(u16x4*)&Ps[w][c * 72 + nt * 16 + quad * 4] = pk; } \
        bf16x8 p0 = ld_bf8(&Ps[w][c * 72 + quad * 8]); \
        bf16x8 p1 = ld_bf8(&Ps[w][c * 72 + 32 + quad * 8]); \
        _Pragma("unroll") for (int kk = 0; kk < 2; ++kk) { \
            bf16x8 pa = kk ? p1 : p0; \
            _Pragma("unroll") for (int ht = 0; ht < 4; ++ht) { \
                bf16x8 va = ld_bf8(&VT[(ht * 16 + c) * 64 + (((kk * 4 + quad) ^ ck7) * 8)]); \
                o[ht] = MFMA(va, pa, o[ht]); } } \
    }

    for (int j0 = jbeg; j0 < jend; j0 += 2) {
        FITER(0, Kt0, Vt0, Kt1, Vt1)
        FITER(1, Kt1, Vt1, Kt0, Vt0)
    }
#undef FITER
#undef FSTAGE

    VM_DRAIN();   // retire tail glds before LDS dealloc at endpgm

    // ---- store partials: slot = blk; pO [slot][row 64][h 64] ----
    unsigned short* po = pO + (size_t)blk * 4096;
#pragma unroll
    for (int ht = 0; ht < 4; ++ht) {
        u16x4 pk;
#pragma unroll
        for (int r = 0; r < 4; ++r) pk[r] = cvt_bf16(o[ht][r]);
        *(u16x4*)(po + (w * 16 + c) * 64 + ht * 16 + quad * 4) = pk;
    }
    if (quad == 0) {
        pml[(size_t)blk * 128 + (w * 16 + c) * 2] = m_run;
        pml[(size_t)blk * 128 + (w * 16 + c) * 2 + 1] = l_run;
    }
}

// ---------------- kernel 4: combine g+1 chunks, one thread per output -------
// 4096 blocks x 256 thr = 1M threads: gid -> (b, qt, row, h); h = lane so
// qt/nc are wave-uniform (no divergence). All <=8 chunk loads issued as a
// fully-unrolled predicated batch (static register indexing, 16 independent
// loads in flight) -> single latency exposure, hidden by TLP. One pass.
__global__ __launch_bounds__(256) void combine_kernel(
        const unsigned short* __restrict__ pO, const float* __restrict__ pml,
        float* __restrict__ out) {
    const int gid = blockIdx.x * 256 + threadIdx.x;
    const int h = gid & 63;
    const int grow = gid >> 6;            // global row 0..16383
    const int b = grow >> 11;
    const int rin = grow & 2047;
    const int qt = rin >> 6;
    const int row = rin & 63;
    const int g = qt >> 2;
    const int nc = g + 1;                 // 1..8 chunks, wave-uniform
    const int s0 = b * 144 + 2 * g * (g + 1) + (qt - 4 * g) * (g + 1);

    float m_[8], l_[8], o_[8];
#pragma unroll
    for (int s = 0; s < 8; ++s) {
        const int slot = s0 + (s < nc ? s : 0);   // clamp: predicated out below
        const float2 ml = *(const float2*)(pml + (size_t)slot * 128 + row * 2);
        const float ov = bf2f(pO[(size_t)slot * 4096 + row * 64 + h]);
        m_[s] = (s < nc) ? ml.x : -3.0e38f;
        l_[s] = (s < nc) ? ml.y : 0.0f;
        o_[s] = (s < nc) ? ov : 0.0f;
    }
    float M = m_[0];
#pragma unroll
    for (int s = 1; s < 8; ++s) M = fmaxf(M, m_[s]);
    float num = 0.0f, den = 0.0f;
#pragma unroll
    for (int s = 0; s < 8; ++s) {
        const float ww = exp2f(m_[s] - M);    // invalid slots -> exp2(-huge)=0
        num += o_[s] * ww;
        den += l_[s] * ww;
    }
    out[(size_t)(b * TT + qt * 64 + row) * HS + h] = num / den;
}

extern "C" void kernel_launch(void* const* d_in, const int* in_sizes, int n_in,
                              void* d_out, int out_size, void* d_ws, size_t ws_size,
                              hipStream_t stream) {
    const float* x  = (const float*)d_in[0];
    const int* pm   = (const int*)d_in[1];
    const float* Wq = (const float*)d_in[2];
    const float* Wk = (const float*)d_in[3];
    const float* Wv = (const float*)d_in[4];
    float* out = (float*)d_out;

    unsigned short* wsu  = (unsigned short*)d_ws;
    unsigned short* wbt  = wsu + WBT_E;
    unsigned short* qws  = wsu + Q_E;
    unsigned short* kws  = wsu + K_E;
    unsigned short* vtws = wsu + VT_E;
    unsigned short* pO   = wsu + PO_E;
    float* pml           = (float*)(wsu + PML_E);

    wconv_kernel<<<48, 256, 0, stream>>>(Wq, Wk, Wv, wbt);
    proj_kernel<<<256, 512, 0, stream>>>(x, wbt, qws, kws, vtws);
    flash_kernel<<<1152, 256, 0, stream>>>(qws, kws, vtws, pm, pO, pml);
    combine_kernel<<<4096, 256, 0, stream>>>(pO, pml, out);
}